// Round 6
// baseline (24.764 us; speedup 1.0000x reference)
//
#include <hip/hip_runtime.h>
#include <cmath>

// VarRateResampler ratio=2: per (b,t) two 21-tap FIRs, polyphase rows chosen
// by an NCO with step s = 64 + acc_phase. Closed form for the NCO state
// entering step t:  a_t = ceil(t*Q/s)*s - t*Q  (invariant a in [0,Q)).
// Flat kernel, TPT=4 x NC=2: each thread produces two INDEPENDENT 4-t chunks
// (t0 and t0+1024) of one row -> 12 loads issue up front, chunk B's compute
// overlaps chunk A's load latency (round-4/5 evidence: single-chain version
// was latency-bound at 42% occupancy, 17% VALUBusy).
//  - stores: REGULAR float4 at 32B lane-stride (round-1 evidence: exact
//    65.5 MB WRITE; round-3 NT variant amplified to 68.7 MB -> NT dropped)
//  - taps via wave-uniform scalar loads (s_load, once per wave)
//  - no LDS, no barrier, no prep kernel

#define QQ   128
#define LT   21
#define TT   4096
#define TPT  4                  // consecutive t per chunk
#define NC   2                  // independent chunks per thread
#define BLK  256
#define SPAN (BLK * TPT)        // 1024 t per chunk-slab
#define TILE (SPAN * NC)        // 2048 t per block

__global__ __launch_bounds__(BLK) void fir_kernel(
    const float* __restrict__ x,
    const float* __restrict__ hs,
    const float* __restrict__ accp,
    float*       __restrict__ y)
{
    const int b   = blockIdx.y;
    const int tid = threadIdx.x;
    const size_t row = (size_t)b * TT;

    int tc[NC];
    #pragma unroll
    for (int c = 0; c < NC; ++c)
        tc[c] = blockIdx.x * TILE + c * SPAN + tid * TPT;

    // ---- load both x windows up front: 2 x 24 floats, 16B-aligned ----
    float xr[NC][24];
    #pragma unroll
    for (int c = 0; c < NC; ++c) {
        const int base = tc[c] - 20;
        if (base >= 0) {
            const float4* src = (const float4*)(x + row + base);  // (4m-20)%4==0
            #pragma unroll
            for (int q = 0; q < 6; ++q) {
                float4 v = src[q];
                xr[c][4*q+0] = v.x; xr[c][4*q+1] = v.y;
                xr[c][4*q+2] = v.z; xr[c][4*q+3] = v.w;
            }
        } else {               // only threads 0..4 of block 0, chunk 0
            #pragma unroll
            for (int i = 0; i < 24; ++i) {
                int gt = base + i;
                xr[c][i] = (gt >= 0) ? x[row + gt] : 0.0f;   // fifo zero-init
            }
        }
    }

    // ---- NCO per chunk: f64 closed-form seed + exact reference recurrence ----
    const float sf = 64.0f + accp[0];                 // step_inc (f32)
    const double s = (double)sf;
    int i0[NC][TPT], i1[NC][TPT];
    #pragma unroll
    for (int c = 0; c < NC; ++c) {
        const double tq0 = (double)tc[c] * 128.0;
        float a = (float)(__builtin_ceil(tq0 / s) * s - tq0);  // acc entering tc
        #pragma unroll
        for (int k = 0; k < TPT; ++k) {
            bool  v0   = a < 128.0f;                  // slot 0
            float ind0 = v0 ? a : -1.0f;
            float ap   = v0 ? a + sf : a;
            bool  v1   = ap < 128.0f;                 // slot 1
            float ind1 = v1 ? ap : -1.0f;
            float an   = v1 ? ap + sf : ap;
            a = an - 128.0f;                          // wrap
            i0[c][k] = min((int)rintf(ind0), QQ - 1); // -1 => NaN row
            i1[c][k] = min((int)rintf(ind1), QQ - 1);
        }
    }

    // ---- wave-uniform fast path check (across lanes, chunks, slots) ----
    bool uni = true;
    #pragma unroll
    for (int c = 0; c < NC; ++c)
        #pragma unroll
        for (int k = 0; k < TPT; ++k)
            uni &= (i0[c][k] == i0[0][0]) & (i1[c][k] == i1[0][0]);
    const int f0 = __builtin_amdgcn_readfirstlane(i0[0][0]);
    const int f1 = __builtin_amdgcn_readfirstlane(i1[0][0]);
    uni &= (i0[0][0] == f0) & (i1[0][0] == f1);

    float out[NC][2 * TPT];

    if (__all(uni) && f0 >= 0 && f1 >= 0) {
        // taps are wave-uniform -> scalar loads into SGPRs, once per wave
        const float* __restrict__ h0 = hs + (size_t)f0 * LT;
        const float* __restrict__ h1 = hs + (size_t)f1 * LT;
        #pragma unroll
        for (int c = 0; c < NC; ++c) {
            #pragma unroll
            for (int k = 0; k < TPT; ++k) {
                float a0 = 0.0f, a1 = 0.0f;
                #pragma unroll
                for (int l = 0; l < LT; ++l) {
                    a0 = fmaf(h0[l], xr[c][k + l], a0);
                    a1 = fmaf(h1[l], xr[c][k + l], a1);
                }
                out[c][2*k]     = a0;
                out[c][2*k + 1] = a1;
            }
        }
    } else {
        // generic per-lane gather path (any acc_phase); correctness-only
        const float NaNf = __int_as_float(0x7fc00000);
        #pragma unroll
        for (int c = 0; c < NC; ++c) {
            #pragma unroll
            for (int k = 0; k < TPT; ++k) {
                const int r0 = i0[c][k], r1 = i1[c][k];
                float a0 = 0.0f, a1 = 0.0f;
                if (r0 >= 0) {
                    const float* hp = hs + (size_t)r0 * LT;
                    #pragma unroll
                    for (int l = 0; l < LT; ++l) a0 = fmaf(hp[l], xr[c][k + l], a0);
                } else a0 = NaNf;
                if (r1 >= 0) {
                    const float* hp = hs + (size_t)r1 * LT;
                    #pragma unroll
                    for (int l = 0; l < LT; ++l) a1 = fmaf(hp[l], xr[c][k + l], a1);
                } else a1 = NaNf;
                out[c][2*k]     = a0;
                out[c][2*k + 1] = a1;
            }
        }
    }

    // ---- write (B, T, 2): per chunk 8 floats = 2 regular float4 stores ----
    #pragma unroll
    for (int c = 0; c < NC; ++c) {
        float4* yq = (float4*)(y + (row + (size_t)tc[c]) * 2);
        yq[0] = make_float4(out[c][0], out[c][1], out[c][2], out[c][3]);
        yq[1] = make_float4(out[c][4], out[c][5], out[c][6], out[c][7]);
    }
}

extern "C" void kernel_launch(void* const* d_in, const int* in_sizes, int n_in,
                              void* d_out, int out_size, void* d_ws, size_t ws_size,
                              hipStream_t stream) {
    const float* x    = (const float*)d_in[0];   // (B, 4096) f32
    const float* hs   = (const float*)d_in[1];   // (128, 21) f32
    const float* accp = (const float*)d_in[2];   // scalar f32
    float* y = (float*)d_out;                    // (B, 4096, 2) f32

    const int B = in_sizes[0] / TT;

    dim3 grid(TT / TILE, B);                     // (2, 2048)
    fir_kernel<<<grid, BLK, 0, stream>>>(x, hs, accp, y);
}

// Round 7
// 23.252 us; speedup vs baseline: 1.0650x; 1.0650x over previous
//
#include <hip/hip_runtime.h>
#include <cmath>

// VarRateResampler ratio=2: per (b,t) two 21-tap FIRs, polyphase rows chosen
// by an NCO with step s = 64 + acc_phase. Closed form for the NCO state
// entering step t:  a_t = ceil(t*Q/s)*s - t*Q  (invariant a in [0,Q)).
// Round-7 = round-5 structure (best, 23.2us: TPT=4, NC=1, no LDS/barrier,
// wave-uniform scalar taps) with exactly ONE memory-path change:
//   stores NT -> REGULAR float4 (round-1/3 evidence: regular merges to the
//   exact 65.5 MB in L2; NT evicted half-filled lines -> 68.7 MB, +4.8%).
// Plus a provably-exact NCO shortcut: step==64.0 => a_t == 0 for all t
// (t*128/64 = 2t integer => m*s - t*128 = 0), removing the per-thread f64
// divide; generic f64 seed kept for any other acc_phase.

#define QQ   128
#define LT   21
#define TT   4096
#define TPT  4                 // t per thread
#define BLK  256
#define TILE (BLK * TPT)       // 1024 t per block

__global__ __launch_bounds__(BLK) void fir_kernel(
    const float* __restrict__ x,
    const float* __restrict__ hs,
    const float* __restrict__ accp,
    float*       __restrict__ y)
{
    const int b  = blockIdx.y;
    const int t0 = blockIdx.x * TILE + threadIdx.x * TPT;
    const size_t row = (size_t)b * TT;

    // ---- x window x[t0-20 .. t0+3] : 24 floats, base (4m-20) is 16B-aligned ----
    float xr[24];
    const int base = t0 - 20;
    if (base >= 0) {
        const float4* src = (const float4*)(x + row + base);
        #pragma unroll
        for (int q = 0; q < 6; ++q) {
            float4 v = src[q];
            xr[4*q+0] = v.x; xr[4*q+1] = v.y; xr[4*q+2] = v.z; xr[4*q+3] = v.w;
        }
    } else {                        // only threads 0..4 of each row's first block
        #pragma unroll
        for (int i = 0; i < 24; ++i) {
            int gt = base + i;
            xr[i] = (gt >= 0) ? x[row + gt] : 0.0f;   // fifo zero-init
        }
    }

    // ---- NCO seed: exact shortcut for s==64, f64 closed form otherwise ----
    const float sf = 64.0f + accp[0];                 // step_inc (f32)
    float a;
    if (sf == 64.0f) {
        a = 0.0f;            // ceil(2t)=2t exactly => a_t = 0 for every t
    } else {
        const double s = (double)sf;
        const double tq0 = (double)t0 * 128.0;
        a = (float)(__builtin_ceil(tq0 / s) * s - tq0);   // acc entering t0
    }

    // ---- exact reference f32 recurrence over the 4 slots ----
    int i0[TPT], i1[TPT];
    #pragma unroll
    for (int k = 0; k < TPT; ++k) {
        bool  v0   = a < 128.0f;                      // slot 0
        float ind0 = v0 ? a : -1.0f;
        float ap   = v0 ? a + sf : a;
        bool  v1   = ap < 128.0f;                     // slot 1
        float ind1 = v1 ? ap : -1.0f;
        float an   = v1 ? ap + sf : ap;
        a = an - 128.0f;                              // wrap
        i0[k] = min((int)rintf(ind0), QQ - 1);        // -1 => NaN row
        i1[k] = min((int)rintf(ind1), QQ - 1);
    }

    // ---- wave-uniform fast path check ----
    bool uni = true;
    #pragma unroll
    for (int k = 1; k < TPT; ++k) uni &= (i0[k] == i0[0]) & (i1[k] == i1[0]);
    const int f0 = __builtin_amdgcn_readfirstlane(i0[0]);
    const int f1 = __builtin_amdgcn_readfirstlane(i1[0]);
    uni &= (i0[0] == f0) & (i1[0] == f1);

    float out[2 * TPT];

    if (__all(uni) && f0 >= 0 && f1 >= 0) {
        // taps are wave-uniform -> scalar loads into SGPRs, once per wave
        const float* __restrict__ h0 = hs + (size_t)f0 * LT;
        const float* __restrict__ h1 = hs + (size_t)f1 * LT;
        #pragma unroll
        for (int k = 0; k < TPT; ++k) {
            float a0 = 0.0f, a1 = 0.0f;
            #pragma unroll
            for (int l = 0; l < LT; ++l) {
                a0 = fmaf(h0[l], xr[k + l], a0);
                a1 = fmaf(h1[l], xr[k + l], a1);
            }
            out[2*k]     = a0;
            out[2*k + 1] = a1;
        }
    } else {
        // generic per-lane gather path (any acc_phase); correctness-only
        const float NaNf = __int_as_float(0x7fc00000);
        #pragma unroll
        for (int k = 0; k < TPT; ++k) {
            const int r0 = i0[k], r1 = i1[k];
            float a0 = 0.0f, a1 = 0.0f;
            if (r0 >= 0) {
                const float* hp = hs + (size_t)r0 * LT;
                #pragma unroll
                for (int l = 0; l < LT; ++l) a0 = fmaf(hp[l], xr[k + l], a0);
            } else a0 = NaNf;
            if (r1 >= 0) {
                const float* hp = hs + (size_t)r1 * LT;
                #pragma unroll
                for (int l = 0; l < LT; ++l) a1 = fmaf(hp[l], xr[k + l], a1);
            } else a1 = NaNf;
            out[2*k]     = a0;
            out[2*k + 1] = a1;
        }
    }

    // ---- write (B, T, 2): 8 floats = 2 REGULAR float4 stores, 32B stride ----
    float4* yq = (float4*)(y + (row + (size_t)t0) * 2);
    yq[0] = make_float4(out[0], out[1], out[2], out[3]);
    yq[1] = make_float4(out[4], out[5], out[6], out[7]);
}

extern "C" void kernel_launch(void* const* d_in, const int* in_sizes, int n_in,
                              void* d_out, int out_size, void* d_ws, size_t ws_size,
                              hipStream_t stream) {
    const float* x    = (const float*)d_in[0];   // (B, 4096) f32
    const float* hs   = (const float*)d_in[1];   // (128, 21) f32
    const float* accp = (const float*)d_in[2];   // scalar f32
    float* y = (float*)d_out;                    // (B, 4096, 2) f32

    const int B = in_sizes[0] / TT;

    dim3 grid(TT / TILE, B);                     // (4, 2048)
    fir_kernel<<<grid, BLK, 0, stream>>>(x, hs, accp, y);
}